// Round 13
// baseline (755.640 us; speedup 1.0000x reference)
//
#include <hip/hip_runtime.h>
#include <hip/hip_bf16.h>
#include <math.h>

#define D 128
#define NH 8
#define DFF 512
#define NG 64
#define NL 4
#define FIN 100
#define SCALE 0.25f
#define QKV 384

typedef __attribute__((ext_vector_type(8))) short short8;
typedef __attribute__((ext_vector_type(4))) float f32x4;

__device__ inline unsigned short f2bf(float v) {
    __hip_bfloat16 b = __float2bfloat16(v);
    return *reinterpret_cast<unsigned short*>(&b);
}

// ---------------- CSR build ----------------
__global__ void count_kernel(const int* __restrict__ dst, int* __restrict__ cnt, int E) {
    int e = blockIdx.x * 256 + threadIdx.x;
    if (e < E) atomicAdd(&cnt[dst[e]], 1);
}

__global__ __launch_bounds__(1024) void scan_block_kernel(const int* __restrict__ cnt,
        int* __restrict__ incl, int* __restrict__ partials, int n) {
    __shared__ int s[1024];
    int tid = threadIdx.x;
    int gid = blockIdx.x * 1024 + tid;
    int val = (gid < n) ? cnt[gid] : 0;
    s[tid] = val;
    __syncthreads();
    for (int o = 1; o < 1024; o <<= 1) {
        int t = (tid >= o) ? s[tid - o] : 0;
        __syncthreads();
        s[tid] += t;
        __syncthreads();
    }
    if (gid < n) incl[gid] = s[tid];
    if (tid == 1023) partials[blockIdx.x] = s[1023];
}

__global__ void scan_partials_kernel(int* __restrict__ partials, int nb) {
    if (threadIdx.x == 0 && blockIdx.x == 0) {
        int run = 0;
        for (int i = 0; i < nb; ++i) { int t = partials[i]; partials[i] = run; run += t; }
    }
}

__global__ void finalize_off_kernel(const int* __restrict__ cnt, const int* __restrict__ incl,
        const int* __restrict__ partials, int* __restrict__ off, int* __restrict__ cur,
        int n, int E) {
    int gid = blockIdx.x * 256 + threadIdx.x;
    if (gid < n) {
        int v = incl[gid] - cnt[gid] + partials[gid >> 10];
        off[gid] = v;
        cur[gid] = v;
    }
    if (gid == 0) off[n] = E;
}

__global__ void scatter_kernel(const int* __restrict__ src, const int* __restrict__ dst,
        int* __restrict__ cur, int* __restrict__ csr_src, int E) {
    int e = blockIdx.x * 256 + threadIdx.x;
    if (e < E) {
        int p = atomicAdd(&cur[dst[e]], 1);
        csr_src[p] = src[e];
    }
}

// ---- weight transpose + bf16 convert: W[K][N] -> Bt[n][k] (out layer stride ldl) ----
__global__ void transpose_cvt_kernel(const float* __restrict__ W, __hip_bfloat16* __restrict__ Bt,
        int K, int N, int ldl) {
    int l = blockIdx.y;
    const float* w = W + (size_t)l * K * N;
    __hip_bfloat16* bt = Bt + (size_t)l * ldl;
    int idx = blockIdx.x * 256 + threadIdx.x;
    if (idx >= K * N) return;
    int n = idx / K, k = idx - n * K;
    bt[(size_t)n * K + k] = __float2bfloat16(w[(size_t)k * N + n]);
}

// ---- embed input pad+cvt: x[N][100] f32 -> xb[N][128] bf16 (zero-padded) ----
__global__ void pad_cvt_x_kernel(const float* __restrict__ x, __hip_bfloat16* __restrict__ xb, int n) {
    int idx = blockIdx.x * 256 + threadIdx.x;
    if (idx >= n * 128) return;
    int r = idx >> 7, c = idx & 127;
    xb[idx] = (c < FIN) ? __float2bfloat16(x[(size_t)r * FIN + c]) : __float2bfloat16(0.f);
}

// ---- W_embed[100][128] -> WembT[128][128] bf16 (k zero-padded) ----
__global__ void wembT_kernel(const float* __restrict__ W, __hip_bfloat16* __restrict__ Bt) {
    int idx = blockIdx.x * 256 + threadIdx.x;
    if (idx >= 128 * 128) return;
    int n = idx >> 7, k = idx & 127;
    Bt[idx] = (k < FIN) ? __float2bfloat16(W[(size_t)k * 128 + n]) : __float2bfloat16(0.f);
}

// ---------------- bf16 MFMA GEMM (embed): A[M,K]@Bt[N,K]^T, tile 128x64, BK=64 ----------------
__global__ __launch_bounds__(256) void gemm_mfma(
        const __hip_bfloat16* __restrict__ A, const __hip_bfloat16* __restrict__ Bt,
        float* __restrict__ Cf, __hip_bfloat16* __restrict__ Cb,
        int M, int N, int K) {
    __shared__ __align__(16) unsigned short As[128][64];
    __shared__ __align__(16) unsigned short Bs[64][64];
    int t = threadIdx.x;
    int wave = t >> 6, lane = t & 63;
    int row0 = blockIdx.x * 128, col0 = blockIdx.y * 64;
    f32x4 acc[2][4] = {};

    int sr = t >> 3;
    int sc = t & 7;

    for (int k0 = 0; k0 < K; k0 += 64) {
#pragma unroll
        for (int i = 0; i < 4; ++i) {
            int r = i * 32 + sr;
            int gr = row0 + r;
            if (gr >= M) gr = M - 1;
            *reinterpret_cast<short8*>(&As[r][(sc ^ (r & 7)) << 3]) =
                *reinterpret_cast<const short8*>(&A[(size_t)gr * K + k0 + (sc << 3)]);
        }
#pragma unroll
        for (int i = 0; i < 2; ++i) {
            int r = i * 32 + sr;
            *reinterpret_cast<short8*>(&Bs[r][(sc ^ (r & 7)) << 3]) =
                *reinterpret_cast<const short8*>(&Bt[(size_t)(col0 + r) * K + k0 + (sc << 3)]);
        }
        __syncthreads();
#pragma unroll
        for (int kk = 0; kk < 64; kk += 32) {
            int lr = lane & 15;
            int kc = (kk >> 3) + (lane >> 4);
            short8 a[2], b[4];
#pragma unroll
            for (int m = 0; m < 2; ++m) {
                int r = wave * 32 + m * 16 + lr;
                a[m] = *reinterpret_cast<const short8*>(&As[r][(kc ^ (r & 7)) << 3]);
            }
#pragma unroll
            for (int n = 0; n < 4; ++n) {
                int r = n * 16 + lr;
                b[n] = *reinterpret_cast<const short8*>(&Bs[r][(kc ^ (r & 7)) << 3]);
            }
#pragma unroll
            for (int m = 0; m < 2; ++m)
#pragma unroll
                for (int n = 0; n < 4; ++n)
                    acc[m][n] = __builtin_amdgcn_mfma_f32_16x16x32_bf16(a[m], b[n], acc[m][n], 0, 0, 0);
        }
        __syncthreads();
    }

    int lr = lane & 15, rg = (lane >> 4) * 4;
#pragma unroll
    for (int m = 0; m < 2; ++m) {
#pragma unroll
        for (int n = 0; n < 4; ++n) {
            int col = col0 + n * 16 + lr;
#pragma unroll
            for (int j = 0; j < 4; ++j) {
                int row = row0 + wave * 32 + m * 16 + rg + j;
                if (row < M) {
                    float val = acc[m][n][j];
                    Cf[(size_t)row * N + col] = val;
                    Cb[(size_t)row * N + col] = __float2bfloat16(val);
                }
            }
        }
    }
}

// ---------------- qkv GEMM, A-resident: qkvb[M,384] = hb[M,128] @ WqkvT[384,128]^T ----------------
__global__ __launch_bounds__(256, 3) void gemm_qkv(
        const __hip_bfloat16* __restrict__ A, const __hip_bfloat16* __restrict__ Bt,
        __hip_bfloat16* __restrict__ Cb, int M) {
    __shared__ __align__(16) unsigned short As[128 * 128];   // 32 KB
    __shared__ __align__(16) unsigned short Bs[64 * 128];    // 16 KB
    int t = threadIdx.x;
    int wave = t >> 6, lane = t & 63;
    int lr = lane & 15, lg = lane >> 4;
    int row0 = blockIdx.x * 128;

    // stage A tile once
#pragma unroll
    for (int i = 0; i < 8; ++i) {
        int idx = t + i * 256;
        int r = idx >> 4, ch = idx & 15;
        int gr = row0 + r; if (gr >= M) gr = M - 1;
        *reinterpret_cast<short8*>(&As[r * 128 + ((ch ^ (r & 7)) << 3)]) =
            *reinterpret_cast<const short8*>(&A[(size_t)gr * 128 + ch * 8]);
    }

    short8 a_all[2][4];
    for (int c = 0; c < 6; ++c) {
        // stage B chunk: rows c*64 .. c*64+63 of WqkvT
#pragma unroll
        for (int i = 0; i < 4; ++i) {
            int idx = t + i * 256;
            int r = idx >> 4, ch = idx & 15;
            *reinterpret_cast<short8*>(&Bs[r * 128 + ((ch ^ (r & 7)) << 3)]) =
                *reinterpret_cast<const short8*>(&Bt[((size_t)(c * 64 + r)) * 128 + ch * 8]);
        }
        __syncthreads();
        if (c == 0) {
#pragma unroll
            for (int m = 0; m < 2; ++m)
#pragma unroll
                for (int ks = 0; ks < 4; ++ks) {
                    int r = wave * 32 + m * 16 + lr;
                    int kc = ks * 4 + lg;
                    a_all[m][ks] = *reinterpret_cast<const short8*>(&As[r * 128 + ((kc ^ (r & 7)) << 3)]);
                }
        }
        f32x4 acc[2][4] = {};
#pragma unroll
        for (int ks = 0; ks < 4; ++ks) {
            int kc = ks * 4 + lg;
            short8 b[4];
#pragma unroll
            for (int n = 0; n < 4; ++n) {
                int r = n * 16 + lr;
                b[n] = *reinterpret_cast<const short8*>(&Bs[r * 128 + ((kc ^ (r & 7)) << 3)]);
            }
#pragma unroll
            for (int m = 0; m < 2; ++m)
#pragma unroll
                for (int n = 0; n < 4; ++n)
                    acc[m][n] = __builtin_amdgcn_mfma_f32_16x16x32_bf16(a_all[m][ks], b[n], acc[m][n], 0, 0, 0);
        }
#pragma unroll
        for (int m = 0; m < 2; ++m)
#pragma unroll
            for (int n = 0; n < 4; ++n) {
                int col = c * 64 + n * 16 + lr;
#pragma unroll
                for (int j = 0; j < 4; ++j) {
                    int row = row0 + wave * 32 + m * 16 + lg * 4 + j;
                    if (row < M)
                        Cb[(size_t)row * QKV + col] = __float2bfloat16(acc[m][n][j]);
                }
            }
        __syncthreads();
    }
}

// ======== fused out-proj + residual + FFN — R5 rhythm/semantics, 48 KB LDS, 3 blocks/CU ========
// h' = h32 + agg@WoutT^T + b_out ; h'' = h' + relu(h'@W1T^T+b1)@W2T^T + b2
// LDS: As 32KB = Wout[128][128] -> h'(bf16) -> {W1s[64][128] | ff1s[128][64]}
//      W2s 16KB = W2 chunk [128][64]
// agg A-fragments: direct global->reg (one-time read; pattern verified in R11 phase 1)
__global__ __launch_bounds__(256, 3) void fused_out_ffn(
        const __hip_bfloat16* __restrict__ aggb, const __hip_bfloat16* __restrict__ WoutT,
        const float* __restrict__ b_out,
        const __hip_bfloat16* __restrict__ W1T, const float* __restrict__ b1,
        const __hip_bfloat16* __restrict__ W2T, const float* __restrict__ b2,
        float* __restrict__ h32, __hip_bfloat16* __restrict__ hb, int M) {
    __shared__ __align__(16) unsigned short As[128 * 128];   // 32 KB
    __shared__ __align__(16) unsigned short W2s[64 * 128];   // 16 KB ([128][64])
    unsigned short* W1s  = As;           // [64][128] (phase 2)
    unsigned short* ff1s = As + 8192;    // [128][64] (phase 2)

    int t = threadIdx.x;
    int wave = t >> 6, lane = t & 63;
    int lr = lane & 15, lg = lane >> 4;
    int row0 = blockIdx.x * 128;

    // ---- agg A-fragments: direct global -> regs (own 32 rows) ----
    short8 a_agg[2][4];
#pragma unroll
    for (int m = 0; m < 2; ++m)
#pragma unroll
        for (int ks = 0; ks < 4; ++ks) {
            int gr = row0 + wave * 32 + m * 16 + lr; if (gr >= M) gr = M - 1;
            a_agg[m][ks] = *reinterpret_cast<const short8*>(&aggb[(size_t)gr * 128 + (ks * 4 + lg) * 8]);
        }

    // ---- stage Wout [128][128] -> As ----
#pragma unroll
    for (int i = 0; i < 8; ++i) {
        int idx = t + i * 256;
        int r = idx >> 4, ch = idx & 15;
        *reinterpret_cast<short8*>(&As[r * 128 + ((ch ^ (r & 7)) << 3)]) =
            *reinterpret_cast<const short8*>(&WoutT[(size_t)r * 128 + ch * 8]);
    }
    __syncthreads();

    // ---- phase 1: acc1 = agg @ Wout^T (K=128, N=128), wave owns 32 rows ----
    f32x4 acc1[2][8] = {};
#pragma unroll
    for (int kk4 = 0; kk4 < 4; ++kk4) {
        int kc = kk4 * 4 + lg;
        short8 b[8];
#pragma unroll
        for (int n = 0; n < 8; ++n) {
            int r = n * 16 + lr;
            b[n] = *reinterpret_cast<const short8*>(&As[r * 128 + ((kc ^ (r & 7)) << 3)]);
        }
#pragma unroll
        for (int m = 0; m < 2; ++m)
#pragma unroll
            for (int n = 0; n < 8; ++n)
                acc1[m][n] = __builtin_amdgcn_mfma_f32_16x16x32_bf16(a_agg[m][kk4], b[n], acc1[m][n], 0, 0, 0);
    }
    __syncthreads();   // all Wout reads complete before h' overwrites As

    // ---- epi1 (R5 semantics): h' = acc1 + b_out + h32 ; write h32 ; bf16 h' -> As own rows ----
#pragma unroll
    for (int m = 0; m < 2; ++m) {
#pragma unroll
        for (int n = 0; n < 8; ++n) {
            int col = n * 16 + lr;
            float bo = b_out[col];
#pragma unroll
            for (int j = 0; j < 4; ++j) {
                int rl = wave * 32 + m * 16 + lg * 4 + j;
                int row = row0 + rl;
                float hv = (row < M) ? h32[(size_t)row * 128 + col] : 0.f;
                float val = acc1[m][n][j] + bo + hv;
                if (row < M) h32[(size_t)row * 128 + col] = val;
                As[rl * 128 + (((col >> 3) ^ (rl & 7)) << 3) + (col & 7)] = f2bf(val);
            }
        }
    }

    // ---- hoist h' A-fragments (own rows; same-wave DS program order) ----
    short8 a_ff[2][4];
#pragma unroll
    for (int m = 0; m < 2; ++m)
#pragma unroll
        for (int ks = 0; ks < 4; ++ks) {
            int r = wave * 32 + m * 16 + lr;
            int kc = ks * 4 + lg;
            a_ff[m][ks] = *reinterpret_cast<const short8*>(&As[r * 128 + ((kc ^ (r & 7)) << 3)]);
        }
    __syncthreads();   // all hoists done before chunk staging overwrites As

    // ---- phase 2: FFN chunk-streamed over DFF in 64-col chunks ----
    f32x4 h2acc[2][8] = {};
    for (int c = 0; c < 8; ++c) {
        if (c > 0) __syncthreads();   // FFN2 reads of W1s/ff1s/W2s done
        // stage W1s [64][128] <- W1T rows c*64..c*64+63
#pragma unroll
        for (int i = 0; i < 4; ++i) {
            int idx = t + i * 256;
            int r = idx >> 4, ch = idx & 15;
            *reinterpret_cast<short8*>(&W1s[r * 128 + ((ch ^ (r & 7)) << 3)]) =
                *reinterpret_cast<const short8*>(&W1T[((size_t)(c * 64 + r)) * 128 + ch * 8]);
        }
        // stage W2s [128][64] <- W2T[:, c*64..c*64+63]
#pragma unroll
        for (int i = 0; i < 4; ++i) {
            int idx = t + i * 256;
            int r = idx >> 3, ch = idx & 7;
            *reinterpret_cast<short8*>(&W2s[r * 64 + ((ch ^ (r & 7)) << 3)]) =
                *reinterpret_cast<const short8*>(&W2T[(size_t)r * 512 + c * 64 + ch * 8]);
        }
        __syncthreads();
        // ffn1 chunk: ff1 = relu(h'(regs) @ W1s^T + b1)
        f32x4 acc2[2][4] = {};
#pragma unroll
        for (int kk4 = 0; kk4 < 4; ++kk4) {
            int kc = kk4 * 4 + lg;
            short8 b[4];
#pragma unroll
            for (int n = 0; n < 4; ++n) {
                int r = n * 16 + lr;
                b[n] = *reinterpret_cast<const short8*>(&W1s[r * 128 + ((kc ^ (r & 7)) << 3)]);
            }
#pragma unroll
            for (int m = 0; m < 2; ++m)
#pragma unroll
                for (int n = 0; n < 4; ++n)
                    acc2[m][n] = __builtin_amdgcn_mfma_f32_16x16x32_bf16(a_ff[m][kk4], b[n], acc2[m][n], 0, 0, 0);
        }
        // relu + bias -> ff1s (own rows only)
#pragma unroll
        for (int m = 0; m < 2; ++m) {
#pragma unroll
            for (int n = 0; n < 4; ++n) {
                int col = n * 16 + lr;
                float bb = b1[c * 64 + col];
#pragma unroll
                for (int j = 0; j < 4; ++j) {
                    int rl = wave * 32 + m * 16 + lg * 4 + j;
                    float val = fmaxf(acc2[m][n][j] + bb, 0.f);
                    ff1s[rl * 64 + (((col >> 3) ^ (rl & 7)) << 3) + (col & 7)] = f2bf(val);
                }
            }
        }
        // ffn2 partial: h2acc += ff1s @ W2s^T  (K=64; own rows, same-wave DS order)
#pragma unroll
        for (int kk4 = 0; kk4 < 2; ++kk4) {
            int kc = kk4 * 4 + lg;
            short8 a[2], b[8];
#pragma unroll
            for (int m = 0; m < 2; ++m) {
                int r = wave * 32 + m * 16 + lr;
                a[m] = *reinterpret_cast<const short8*>(&ff1s[r * 64 + ((kc ^ (r & 7)) << 3)]);
            }
#pragma unroll
            for (int n = 0; n < 8; ++n) {
                int r = n * 16 + lr;
                b[n] = *reinterpret_cast<const short8*>(&W2s[r * 64 + ((kc ^ (r & 7)) << 3)]);
            }
#pragma unroll
            for (int m = 0; m < 2; ++m)
#pragma unroll
                for (int n = 0; n < 8; ++n)
                    h2acc[m][n] = __builtin_amdgcn_mfma_f32_16x16x32_bf16(a[m], b[n], h2acc[m][n], 0, 0, 0);
        }
    }

    // ---- phase 3 (R5): h'' = h2acc + b2 + h' (h32 re-read, L2-hot) ----
#pragma unroll
    for (int m = 0; m < 2; ++m) {
#pragma unroll
        for (int n = 0; n < 8; ++n) {
            int col = n * 16 + lr;
            float bb = b2[col];
#pragma unroll
            for (int j = 0; j < 4; ++j) {
                int row = row0 + wave * 32 + m * 16 + lg * 4 + j;
                if (row < M) {
                    float val = h2acc[m][n][j] + bb + h32[(size_t)row * 128 + col];
                    h32[(size_t)row * 128 + col] = val;
                    hb[(size_t)row * 128 + col] = __float2bfloat16(val);
                }
            }
        }
    }
}

// ------- attention: wave/dst, 8-edge blocked online softmax, fused qkv rows -------
__global__ __launch_bounds__(256) void attn_kernel(const __hip_bfloat16* __restrict__ qkvb,
        const int* __restrict__ off, const int* __restrict__ csr_src,
        __hip_bfloat16* __restrict__ aggb, int n) {
    int wave = threadIdx.x >> 6;
    int lane = threadIdx.x & 63;
    int i = blockIdx.x * 4 + wave;
    if (i >= n) return;
    const unsigned* qv = reinterpret_cast<const unsigned*>(qkvb);
    unsigned ku = qv[(size_t)i * 192 + 64 + lane];
    float kx = __uint_as_float(ku << 16);
    float ky = __uint_as_float(ku & 0xffff0000u);
    int e0 = off[i], e1 = off[i + 1];
    float m = -INFINITY, ssum = 0.f, ax = 0.f, ay = 0.f;
    int e = e0;
    // ---- 8-edge main loop: 16 row loads in flight, one rescale per 8 edges ----
    for (; e + 8 <= e1; e += 8) {
        int s[8];
#pragma unroll
        for (int u = 0; u < 8; ++u) s[u] = csr_src[e + u];
        unsigned q[8], w[8];
#pragma unroll
        for (int u = 0; u < 8; ++u) {
            q[u] = qv[(size_t)s[u] * 192 + lane];
            w[u] = qv[(size_t)s[u] * 192 + 128 + lane];
        }
        float l[8];
#pragma unroll
        for (int u = 0; u < 8; ++u)
            l[u] = __uint_as_float(q[u] << 16) * kx + __uint_as_float(q[u] & 0xffff0000u) * ky;
#pragma unroll
        for (int u = 0; u < 8; ++u) {
            l[u] += __shfl_xor(l[u], 1);
            l[u] += __shfl_xor(l[u], 2);
            l[u] += __shfl_xor(l[u], 4);
            l[u] *= SCALE;
        }
        float mx = fmaxf(fmaxf(fmaxf(l[0], l[1]), fmaxf(l[2], l[3])),
                         fmaxf(fmaxf(l[4], l[5]), fmaxf(l[6], l[7])));
        float mn = fmaxf(m, mx);
        float corr = __expf(m - mn);
        float psum = 0.f, axn = 0.f, ayn = 0.f;
#pragma unroll
        for (int u = 0; u < 8; ++u) {
            float pe = __expf(l[u] - mn);
            psum += pe;
            axn += pe * __uint_as_float(w[u] << 16);
            ayn += pe * __uint_as_float(w[u] & 0xffff0000u);
        }
        ssum = ssum * corr + psum;
        ax = ax * corr + axn;
        ay = ay * corr + ayn;
        m = mn;
    }
    // ---- 4-edge remainder ----
    for (; e + 4 <= e1; e += 4) {
        int s0 = csr_src[e], s1 = csr_src[e + 1], s2 = csr_src[e + 2], s3 = csr_src[e + 3];
        unsigned q0 = qv[(size_t)s0 * 192 + lane];
        unsigned q1 = qv[(size_t)s1 * 192 + lane];
        unsigned q2 = qv[(size_t)s2 * 192 + lane];
        unsigned q3 = qv[(size_t)s3 * 192 + lane];
        unsigned w0 = qv[(size_t)s0 * 192 + 128 + lane];
        unsigned w1 = qv[(size_t)s1 * 192 + 128 + lane];
        unsigned w2 = qv[(size_t)s2 * 192 + 128 + lane];
        unsigned w3 = qv[(size_t)s3 * 192 + 128 + lane];
        float l0 = __uint_as_float(q0 << 16) * kx + __uint_as_float(q0 & 0xffff0000u) * ky;
        float l1 = __uint_as_float(q1 << 16) * kx + __uint_as_float(q1 & 0xffff0000u) * ky;
        float l2 = __uint_as_float(q2 << 16) * kx + __uint_as_float(q2 & 0xffff0000u) * ky;
        float l3 = __uint_as_float(q3 << 16) * kx + __uint_as_float(q3 & 0xffff0000u) * ky;
        l0 += __shfl_xor(l0, 1); l1 += __shfl_xor(l1, 1); l2 += __shfl_xor(l2, 1); l3 += __shfl_xor(l3, 1);
        l0 += __shfl_xor(l0, 2); l1 += __shfl_xor(l1, 2); l2 += __shfl_xor(l2, 2); l3 += __shfl_xor(l3, 2);
        l0 += __shfl_xor(l0, 4); l1 += __shfl_xor(l1, 4); l2 += __shfl_xor(l2, 4); l3 += __shfl_xor(l3, 4);
        l0 *= SCALE; l1 *= SCALE; l2 *= SCALE; l3 *= SCALE;
        float mx = fmaxf(fmaxf(l0, l1), fmaxf(l2, l3));
        float mn = fmaxf(m, mx);
        float corr = __expf(m - mn);
        float p0 = __expf(l0 - mn);
        float p1 = __expf(l1 - mn);
        float p2 = __expf(l2 - mn);
        float p3 = __expf(l3 - mn);
        ssum = ssum * corr + ((p0 + p1) + (p2 + p3));
        ax = ax * corr + p0 * __uint_as_float(w0 << 16) + p1 * __uint_as_float(w1 << 16)
                       + p2 * __uint_as_float(w2 << 16) + p3 * __uint_as_float(w3 << 16);
        ay = ay * corr + p0 * __uint_as_float(w0 & 0xffff0000u) + p1 * __uint_as_float(w1 & 0xffff0000u)
                       + p2 * __uint_as_float(w2 & 0xffff0000u) + p3 * __uint_as_float(w3 & 0xffff0000u);
        m = mn;
    }
    // ---- scalar remainder ----
    for (; e < e1; ++e) {
        int s0 = csr_src[e];
        unsigned q0 = qv[(size_t)s0 * 192 + lane];
        unsigned w0 = qv[(size_t)s0 * 192 + 128 + lane];
        float l0 = __uint_as_float(q0 << 16) * kx + __uint_as_float(q0 & 0xffff0000u) * ky;
        l0 += __shfl_xor(l0, 1); l0 += __shfl_xor(l0, 2); l0 += __shfl_xor(l0, 4);
        l0 *= SCALE;
        float mn = fmaxf(m, l0);
        float corr = __expf(m - mn);
        float pe = __expf(l0 - mn);
        ssum = ssum * corr + pe;
        ax = ax * corr + pe * __uint_as_float(w0 << 16);
        ay = ay * corr + pe * __uint_as_float(w0 & 0xffff0000u);
        m = mn;
    }
    float inv = (ssum > 0.f) ? 1.f / ssum : 0.f;
    __hip_bfloat162 o;
    o.x = __float2bfloat16(ax * inv);
    o.y = __float2bfloat16(ay * inv);
    *reinterpret_cast<__hip_bfloat162*>(aggb + (size_t)i * 128 + lane * 2) = o;
}

// ---------------- pooling (deterministic two-stage, batch sorted) ----------------
__global__ void group_bounds_kernel(const int* __restrict__ batch, int n, int* __restrict__ gstart) {
    int g = threadIdx.x;
    if (g > NG) return;
    int lo = 0, hi = n;
    while (lo < hi) {
        int mid = (lo + hi) >> 1;
        if (batch[mid] < g) lo = mid + 1; else hi = mid;
    }
    gstart[g] = lo;
}

__global__ __launch_bounds__(256) void pool_stage1(const float* __restrict__ h,
        const int* __restrict__ gstart, float* __restrict__ pws) {
    int g = blockIdx.x, sub = blockIdx.y;
    int s = gstart[g], e = gstart[g + 1];
    int c = threadIdx.x & 127;
    int half = threadIdx.x >> 7;
    float acc = 0.f;
    for (int r = s + sub * 2 + half; r < e; r += 16)
        acc += h[(size_t)r * 128 + c];
    __shared__ float tmp[2][128];
    tmp[half][c] = acc;
    __syncthreads();
    if (half == 0)
        pws[((size_t)g * 8 + sub) * 128 + c] = tmp[0][c] + tmp[1][c];
}

__global__ void pool_stage2(const float* __restrict__ pws, const int* __restrict__ gstart,
        float* __restrict__ out) {
    int g = blockIdx.x, c = threadIdx.x;
    float s = 0.f;
#pragma unroll
    for (int i = 0; i < 8; ++i) s += pws[((size_t)g * 8 + i) * 128 + c];
    float cntf = (float)(gstart[g + 1] - gstart[g]);
    out[(size_t)g * 128 + c] = s / fmaxf(cntf, 1.f);
}

extern "C" void kernel_launch(void* const* d_in, const int* in_sizes, int n_in,
                              void* d_out, int out_size, void* d_ws, size_t ws_size,
                              hipStream_t stream) {
    const float* x = (const float*)d_in[0];
    const int* ei = (const int*)d_in[1];
    const int* batch = (const int*)d_in[2];
    const float* W_embed = (const float*)d_in[3];
    const float* Wqk = (const float*)d_in[4];
    const float* Wv = (const float*)d_in[5];
    const float* Wout = (const float*)d_in[6];
    const float* b_out = (const float*)d_in[7];
    const float* W1 = (const float*)d_in[8];
    const float* b1 = (const float*)d_in[9];
    const float* W2 = (const float*)d_in[10];
    const float* b2 = (const float*)d_in[11];

    int Nn = in_sizes[2];
    int E = in_sizes[1] / 2;

    char* p = (char*)d_ws;
    auto alloc = [&](size_t bytes) {
        char* r = p;
        p += (bytes + 255) & ~(size_t)255;
        return r;
    };
    float* h32 = (float*)alloc((size_t)Nn * D * 4);
    __hip_bfloat16* hb = (__hip_bfloat16*)alloc((size_t)Nn * D * 2);
    __hip_bfloat16* aggb = (__hip_bfloat16*)alloc((size_t)Nn * D * 2);
    __hip_bfloat16* qkvb = (__hip_bfloat16*)alloc((size_t)Nn * QKV * 2);
    __hip_bfloat16* xb = (__hip_bfloat16*)alloc((size_t)Nn * D * 2);
    __hip_bfloat16* WembT = (__hip_bfloat16*)alloc((size_t)D * D * 2);
    __hip_bfloat16* WqkvT = (__hip_bfloat16*)alloc((size_t)NL * QKV * D * 2);
    __hip_bfloat16* WoutT = (__hip_bfloat16*)alloc((size_t)NL * D * D * 2);
    __hip_bfloat16* W1T = (__hip_bfloat16*)alloc((size_t)NL * D * DFF * 2);
    __hip_bfloat16* W2T = (__hip_bfloat16*)alloc((size_t)NL * DFF * D * 2);
    int* csr_src = (int*)alloc((size_t)E * 4);
    int* cnt = (int*)alloc((size_t)Nn * 4);
    int* incl = (int*)alloc((size_t)Nn * 4);
    int* off = (int*)alloc(((size_t)Nn + 1) * 4);
    int* cur = (int*)alloc((size_t)Nn * 4);
    int* partials = (int*)alloc(1024 * 4);
    int* gstart = (int*)alloc((NG + 1) * 4);
    float* pws = (float*)alloc((size_t)NG * 8 * 128 * 4);

    const int* e_src = ei;
    const int* e_dst = ei + E;

    // CSR build (by dst)
    hipMemsetAsync(cnt, 0, (size_t)Nn * 4, stream);
    count_kernel<<<(E + 255) / 256, 256, 0, stream>>>(e_dst, cnt, E);
    int nsb = (Nn + 1023) / 1024;
    scan_block_kernel<<<nsb, 1024, 0, stream>>>(cnt, incl, partials, Nn);
    scan_partials_kernel<<<1, 64, 0, stream>>>(partials, nsb);
    finalize_off_kernel<<<(Nn + 255) / 256, 256, 0, stream>>>(cnt, incl, partials, off, cur, Nn, E);
    scatter_kernel<<<(E + 255) / 256, 256, 0, stream>>>(e_src, e_dst, cur, csr_src, E);

    // weight prep
    transpose_cvt_kernel<<<dim3((2 * D * D + 255) / 256, NL), 256, 0, stream>>>(
        Wqk, WqkvT, D, 2 * D, QKV * D);
    transpose_cvt_kernel<<<dim3((D * D + 255) / 256, NL), 256, 0, stream>>>(
        Wv, WqkvT + (size_t)2 * D * D, D, D, QKV * D);
    transpose_cvt_kernel<<<dim3((D * D + 255) / 256, NL), 256, 0, stream>>>(
        Wout, WoutT, D, D, D * D);
    transpose_cvt_kernel<<<dim3((D * DFF + 255) / 256, NL), 256, 0, stream>>>(
        W1, W1T, D, DFF, D * DFF);
    transpose_cvt_kernel<<<dim3((DFF * D + 255) / 256, NL), 256, 0, stream>>>(
        W2, W2T, DFF, D, DFF * D);
    wembT_kernel<<<(128 * 128 + 255) / 256, 256, 0, stream>>>(W_embed, WembT);
    pad_cvt_x_kernel<<<((size_t)Nn * 128 + 255) / 256, 256, 0, stream>>>(x, xb, Nn);

    int gmb = (Nn + 127) / 128;
    // embed via MFMA: h32 + hb = xb @ WembT^T
    gemm_mfma<<<dim3(gmb, D / 64), 256, 0, stream>>>(xb, WembT, h32, hb, Nn, D, D);

    for (int l = 0; l < NL; ++l) {
        gemm_qkv<<<gmb, 256, 0, stream>>>(hb, WqkvT + (size_t)l * QKV * D, qkvb, Nn);
        attn_kernel<<<(Nn + 3) / 4, 256, 0, stream>>>(qkvb, off, csr_src, aggb, Nn);
        fused_out_ffn<<<gmb, 256, 0, stream>>>(
            aggb, WoutT + (size_t)l * D * D, b_out + (size_t)l * D,
            W1T + (size_t)l * D * DFF, b1 + (size_t)l * DFF,
            W2T + (size_t)l * DFF * D, b2 + (size_t)l * D,
            h32, hb, Nn);
    }

    group_bounds_kernel<<<1, 128, 0, stream>>>(batch, Nn, gstart);
    pool_stage1<<<dim3(NG, 8), 256, 0, stream>>>(h32, gstart, pws);
    pool_stage2<<<NG, 128, 0, stream>>>(pws, gstart, (float*)d_out);
}

// Round 14
// 637.266 us; speedup vs baseline: 1.1858x; 1.1858x over previous
//
#include <hip/hip_runtime.h>
#include <hip/hip_bf16.h>
#include <math.h>

#define D 128
#define NH 8
#define DFF 512
#define NG 64
#define NL 4
#define FIN 100
#define SCALE 0.25f
#define QKV 384

typedef __attribute__((ext_vector_type(8))) short short8;
typedef __attribute__((ext_vector_type(4))) float f32x4;

__device__ inline unsigned short f2bf(float v) {
    __hip_bfloat16 b = __float2bfloat16(v);
    return *reinterpret_cast<unsigned short*>(&b);
}

// ---------------- CSR build ----------------
__global__ void count_kernel(const int* __restrict__ dst, int* __restrict__ cnt, int E) {
    int e = blockIdx.x * 256 + threadIdx.x;
    if (e < E) atomicAdd(&cnt[dst[e]], 1);
}

__global__ __launch_bounds__(1024) void scan_block_kernel(const int* __restrict__ cnt,
        int* __restrict__ incl, int* __restrict__ partials, int n) {
    __shared__ int s[1024];
    int tid = threadIdx.x;
    int gid = blockIdx.x * 1024 + tid;
    int val = (gid < n) ? cnt[gid] : 0;
    s[tid] = val;
    __syncthreads();
    for (int o = 1; o < 1024; o <<= 1) {
        int t = (tid >= o) ? s[tid - o] : 0;
        __syncthreads();
        s[tid] += t;
        __syncthreads();
    }
    if (gid < n) incl[gid] = s[tid];
    if (tid == 1023) partials[blockIdx.x] = s[1023];
}

__global__ void scan_partials_kernel(int* __restrict__ partials, int nb) {
    if (threadIdx.x == 0 && blockIdx.x == 0) {
        int run = 0;
        for (int i = 0; i < nb; ++i) { int t = partials[i]; partials[i] = run; run += t; }
    }
}

__global__ void finalize_off_kernel(const int* __restrict__ cnt, const int* __restrict__ incl,
        const int* __restrict__ partials, int* __restrict__ off, int* __restrict__ cur,
        int n, int E) {
    int gid = blockIdx.x * 256 + threadIdx.x;
    if (gid < n) {
        int v = incl[gid] - cnt[gid] + partials[gid >> 10];
        off[gid] = v;
        cur[gid] = v;
    }
    if (gid == 0) off[n] = E;
}

__global__ void scatter_kernel(const int* __restrict__ src, const int* __restrict__ dst,
        int* __restrict__ cur, int* __restrict__ csr_src, int E) {
    int e = blockIdx.x * 256 + threadIdx.x;
    if (e < E) {
        int p = atomicAdd(&cur[dst[e]], 1);
        csr_src[p] = src[e];
    }
}

// ---- weight transpose + bf16 convert: W[K][N] -> Bt[n][k] (out layer stride ldl) ----
__global__ void transpose_cvt_kernel(const float* __restrict__ W, __hip_bfloat16* __restrict__ Bt,
        int K, int N, int ldl) {
    int l = blockIdx.y;
    const float* w = W + (size_t)l * K * N;
    __hip_bfloat16* bt = Bt + (size_t)l * ldl;
    int idx = blockIdx.x * 256 + threadIdx.x;
    if (idx >= K * N) return;
    int n = idx / K, k = idx - n * K;
    bt[(size_t)n * K + k] = __float2bfloat16(w[(size_t)k * N + n]);
}

// ---- embed input pad+cvt: x[N][100] f32 -> xb[N][128] bf16 (zero-padded) ----
__global__ void pad_cvt_x_kernel(const float* __restrict__ x, __hip_bfloat16* __restrict__ xb, int n) {
    int idx = blockIdx.x * 256 + threadIdx.x;
    if (idx >= n * 128) return;
    int r = idx >> 7, c = idx & 127;
    xb[idx] = (c < FIN) ? __float2bfloat16(x[(size_t)r * FIN + c]) : __float2bfloat16(0.f);
}

// ---- W_embed[100][128] -> WembT[128][128] bf16 (k zero-padded) ----
__global__ void wembT_kernel(const float* __restrict__ W, __hip_bfloat16* __restrict__ Bt) {
    int idx = blockIdx.x * 256 + threadIdx.x;
    if (idx >= 128 * 128) return;
    int n = idx >> 7, k = idx & 127;
    Bt[idx] = (k < FIN) ? __float2bfloat16(W[(size_t)k * 128 + n]) : __float2bfloat16(0.f);
}

// ---------------- bf16 MFMA GEMM (embed): A[M,K]@Bt[N,K]^T, tile 128x64, BK=64 ----------------
__global__ __launch_bounds__(256) void gemm_mfma(
        const __hip_bfloat16* __restrict__ A, const __hip_bfloat16* __restrict__ Bt,
        float* __restrict__ Cf, __hip_bfloat16* __restrict__ Cb,
        int M, int N, int K) {
    __shared__ __align__(16) unsigned short As[128][64];
    __shared__ __align__(16) unsigned short Bs[64][64];
    int t = threadIdx.x;
    int wave = t >> 6, lane = t & 63;
    int row0 = blockIdx.x * 128, col0 = blockIdx.y * 64;
    f32x4 acc[2][4] = {};

    int sr = t >> 3;
    int sc = t & 7;

    for (int k0 = 0; k0 < K; k0 += 64) {
#pragma unroll
        for (int i = 0; i < 4; ++i) {
            int r = i * 32 + sr;
            int gr = row0 + r;
            if (gr >= M) gr = M - 1;
            *reinterpret_cast<short8*>(&As[r][(sc ^ (r & 7)) << 3]) =
                *reinterpret_cast<const short8*>(&A[(size_t)gr * K + k0 + (sc << 3)]);
        }
#pragma unroll
        for (int i = 0; i < 2; ++i) {
            int r = i * 32 + sr;
            *reinterpret_cast<short8*>(&Bs[r][(sc ^ (r & 7)) << 3]) =
                *reinterpret_cast<const short8*>(&Bt[(size_t)(col0 + r) * K + k0 + (sc << 3)]);
        }
        __syncthreads();
#pragma unroll
        for (int kk = 0; kk < 64; kk += 32) {
            int lr = lane & 15;
            int kc = (kk >> 3) + (lane >> 4);
            short8 a[2], b[4];
#pragma unroll
            for (int m = 0; m < 2; ++m) {
                int r = wave * 32 + m * 16 + lr;
                a[m] = *reinterpret_cast<const short8*>(&As[r][(kc ^ (r & 7)) << 3]);
            }
#pragma unroll
            for (int n = 0; n < 4; ++n) {
                int r = n * 16 + lr;
                b[n] = *reinterpret_cast<const short8*>(&Bs[r][(kc ^ (r & 7)) << 3]);
            }
#pragma unroll
            for (int m = 0; m < 2; ++m)
#pragma unroll
                for (int n = 0; n < 4; ++n)
                    acc[m][n] = __builtin_amdgcn_mfma_f32_16x16x32_bf16(a[m], b[n], acc[m][n], 0, 0, 0);
        }
        __syncthreads();
    }

    int lr = lane & 15, rg = (lane >> 4) * 4;
#pragma unroll
    for (int m = 0; m < 2; ++m) {
#pragma unroll
        for (int n = 0; n < 4; ++n) {
            int col = col0 + n * 16 + lr;
#pragma unroll
            for (int j = 0; j < 4; ++j) {
                int row = row0 + wave * 32 + m * 16 + rg + j;
                if (row < M) {
                    float val = acc[m][n][j];
                    Cf[(size_t)row * N + col] = val;
                    Cb[(size_t)row * N + col] = __float2bfloat16(val);
                }
            }
        }
    }
}

// ---------------- qkv GEMM, A-resident: qkvb[M,384] = hb[M,128] @ WqkvT[384,128]^T ----------------
__global__ __launch_bounds__(256, 3) void gemm_qkv(
        const __hip_bfloat16* __restrict__ A, const __hip_bfloat16* __restrict__ Bt,
        __hip_bfloat16* __restrict__ Cb, int M) {
    __shared__ __align__(16) unsigned short As[128 * 128];   // 32 KB
    __shared__ __align__(16) unsigned short Bs[64 * 128];    // 16 KB
    int t = threadIdx.x;
    int wave = t >> 6, lane = t & 63;
    int lr = lane & 15, lg = lane >> 4;
    int row0 = blockIdx.x * 128;

    // stage A tile once
#pragma unroll
    for (int i = 0; i < 8; ++i) {
        int idx = t + i * 256;
        int r = idx >> 4, ch = idx & 15;
        int gr = row0 + r; if (gr >= M) gr = M - 1;
        *reinterpret_cast<short8*>(&As[r * 128 + ((ch ^ (r & 7)) << 3)]) =
            *reinterpret_cast<const short8*>(&A[(size_t)gr * 128 + ch * 8]);
    }

    short8 a_all[2][4];
    for (int c = 0; c < 6; ++c) {
        // stage B chunk: rows c*64 .. c*64+63 of WqkvT
#pragma unroll
        for (int i = 0; i < 4; ++i) {
            int idx = t + i * 256;
            int r = idx >> 4, ch = idx & 15;
            *reinterpret_cast<short8*>(&Bs[r * 128 + ((ch ^ (r & 7)) << 3)]) =
                *reinterpret_cast<const short8*>(&Bt[((size_t)(c * 64 + r)) * 128 + ch * 8]);
        }
        __syncthreads();
        if (c == 0) {
#pragma unroll
            for (int m = 0; m < 2; ++m)
#pragma unroll
                for (int ks = 0; ks < 4; ++ks) {
                    int r = wave * 32 + m * 16 + lr;
                    int kc = ks * 4 + lg;
                    a_all[m][ks] = *reinterpret_cast<const short8*>(&As[r * 128 + ((kc ^ (r & 7)) << 3)]);
                }
        }
        f32x4 acc[2][4] = {};
#pragma unroll
        for (int ks = 0; ks < 4; ++ks) {
            int kc = ks * 4 + lg;
            short8 b[4];
#pragma unroll
            for (int n = 0; n < 4; ++n) {
                int r = n * 16 + lr;
                b[n] = *reinterpret_cast<const short8*>(&Bs[r * 128 + ((kc ^ (r & 7)) << 3)]);
            }
#pragma unroll
            for (int m = 0; m < 2; ++m)
#pragma unroll
                for (int n = 0; n < 4; ++n)
                    acc[m][n] = __builtin_amdgcn_mfma_f32_16x16x32_bf16(a_all[m][ks], b[n], acc[m][n], 0, 0, 0);
        }
#pragma unroll
        for (int m = 0; m < 2; ++m)
#pragma unroll
            for (int n = 0; n < 4; ++n) {
                int col = c * 64 + n * 16 + lr;
#pragma unroll
                for (int j = 0; j < 4; ++j) {
                    int row = row0 + wave * 32 + m * 16 + lg * 4 + j;
                    if (row < M)
                        Cb[(size_t)row * QKV + col] = __float2bfloat16(acc[m][n][j]);
                }
            }
        __syncthreads();
    }
}

// ======== fused out-proj + residual + FFN (R5 verbatim — measured 68 us) ========
// h' = h32 + agg@WoutT^T + b_out ; h'' = h' + relu(h'@W1T^T+b1)@W2T^T + b2
// LDS (dynamic 80KB):
//   region0 [128][128] : A-stage (aggb) -> reused in-place as hbT (bf16 h')
//   region1 [128][128] : phase1 WoutT ; phase2 W1s[64][128] + ff1s[128][64]
//   region2 [128][64]  : W2s chunk
__global__ __launch_bounds__(256) void fused_out_ffn(
        const __hip_bfloat16* __restrict__ aggb, const __hip_bfloat16* __restrict__ WoutT,
        const float* __restrict__ b_out,
        const __hip_bfloat16* __restrict__ W1T, const float* __restrict__ b1,
        const __hip_bfloat16* __restrict__ W2T, const float* __restrict__ b2,
        float* __restrict__ h32, __hip_bfloat16* __restrict__ hb, int M) {
    extern __shared__ __align__(16) unsigned short smem[];
    unsigned short* As  = smem;              // 16384 shorts
    unsigned short* Bs  = smem + 16384;      // 16384 shorts
    unsigned short* W1s = Bs;                // [64][128] = 8192
    unsigned short* ff1s = Bs + 8192;        // [128][64] = 8192
    unsigned short* W2s = smem + 32768;      // [128][64] = 8192

    int t = threadIdx.x;
    int wave = t >> 6, lane = t & 63;
    int lr = lane & 15, lg = lane >> 4;
    int row0 = blockIdx.x * 128;

    // ---- stage A (agg tile) and B (WoutT), both [128][128], 16B-chunk XOR swizzle ----
#pragma unroll
    for (int i = 0; i < 8; ++i) {
        int idx = t + i * 256;          // 0..2047
        int r = idx >> 4, ch = idx & 15;
        int gr = row0 + r; if (gr >= M) gr = M - 1;
        *reinterpret_cast<short8*>(&As[r * 128 + ((ch ^ (r & 7)) << 3)]) =
            *reinterpret_cast<const short8*>(&aggb[(size_t)gr * 128 + ch * 8]);
        *reinterpret_cast<short8*>(&Bs[r * 128 + ((ch ^ (r & 7)) << 3)]) =
            *reinterpret_cast<const short8*>(&WoutT[(size_t)r * 128 + ch * 8]);
    }
    __syncthreads();

    // ---- phase 1: out = A @ WoutT^T  (K=128, full N=128), wave owns 32 rows ----
    f32x4 acc1[2][8] = {};
#pragma unroll
    for (int kk4 = 0; kk4 < 4; ++kk4) {
        int kc = kk4 * 4 + lg;
        short8 a[2], b[8];
#pragma unroll
        for (int m = 0; m < 2; ++m) {
            int r = wave * 32 + m * 16 + lr;
            a[m] = *reinterpret_cast<const short8*>(&As[r * 128 + ((kc ^ (r & 7)) << 3)]);
        }
#pragma unroll
        for (int n = 0; n < 8; ++n) {
            int r = n * 16 + lr;
            b[n] = *reinterpret_cast<const short8*>(&Bs[r * 128 + ((kc ^ (r & 7)) << 3)]);
        }
#pragma unroll
        for (int m = 0; m < 2; ++m)
#pragma unroll
            for (int n = 0; n < 8; ++n)
                acc1[m][n] = __builtin_amdgcn_mfma_f32_16x16x32_bf16(a[m], b[n], acc1[m][n], 0, 0, 0);
    }

    // ---- phase 1 epilogue: h' = out + b_out + h32 ; write h32, hbT(LDS, in-place over As) ----
#pragma unroll
    for (int m = 0; m < 2; ++m) {
#pragma unroll
        for (int n = 0; n < 8; ++n) {
            int col = n * 16 + lr;
            float bo = b_out[col];
#pragma unroll
            for (int j = 0; j < 4; ++j) {
                int rl = wave * 32 + m * 16 + lg * 4 + j;
                int row = row0 + rl;
                float hv = (row < M) ? h32[(size_t)row * 128 + col] : 0.f;
                float val = acc1[m][n][j] + bo + hv;
                if (row < M) h32[(size_t)row * 128 + col] = val;
                As[rl * 128 + (((col >> 3) ^ (rl & 7)) << 3) + (col & 7)] = f2bf(val);
            }
        }
    }

    // ---- phase 2: FFN chunk-streamed over DFF in 64-col chunks ----
    f32x4 h2acc[2][8] = {};
    for (int c = 0; c < 8; ++c) {
        __syncthreads();   // everyone done reading W1s/ff1s/W2s (or As/Bs phase-1 data when c==0)
        // stage W1s [64][128] <- W1T rows c*64..c*64+63
#pragma unroll
        for (int i = 0; i < 4; ++i) {
            int idx = t + i * 256;      // 0..1023
            int r = idx >> 4, ch = idx & 15;
            *reinterpret_cast<short8*>(&W1s[r * 128 + ((ch ^ (r & 7)) << 3)]) =
                *reinterpret_cast<const short8*>(&W1T[((size_t)(c * 64 + r)) * 128 + ch * 8]);
        }
        // stage W2s [128][64] <- W2T[:, c*64..c*64+63]
#pragma unroll
        for (int i = 0; i < 4; ++i) {
            int idx = t + i * 256;
            int r = idx >> 3, ch = idx & 7;
            *reinterpret_cast<short8*>(&W2s[r * 64 + ((ch ^ (r & 7)) << 3)]) =
                *reinterpret_cast<const short8*>(&W2T[(size_t)r * 512 + c * 64 + ch * 8]);
        }
        __syncthreads();
        // ffn1 chunk: ff1 = relu(hbT @ W1s^T + b1)
        f32x4 acc2[2][4] = {};
#pragma unroll
        for (int kk4 = 0; kk4 < 4; ++kk4) {
            int kc = kk4 * 4 + lg;
            short8 a[2], b[4];
#pragma unroll
            for (int m = 0; m < 2; ++m) {
                int r = wave * 32 + m * 16 + lr;
                a[m] = *reinterpret_cast<const short8*>(&As[r * 128 + ((kc ^ (r & 7)) << 3)]);
            }
#pragma unroll
            for (int n = 0; n < 4; ++n) {
                int r = n * 16 + lr;
                b[n] = *reinterpret_cast<const short8*>(&W1s[r * 128 + ((kc ^ (r & 7)) << 3)]);
            }
#pragma unroll
            for (int m = 0; m < 2; ++m)
#pragma unroll
                for (int n = 0; n < 4; ++n)
                    acc2[m][n] = __builtin_amdgcn_mfma_f32_16x16x32_bf16(a[m], b[n], acc2[m][n], 0, 0, 0);
        }
        // relu + bias -> ff1s (own rows only)
#pragma unroll
        for (int m = 0; m < 2; ++m) {
#pragma unroll
            for (int n = 0; n < 4; ++n) {
                int col = n * 16 + lr;
                float bb = b1[c * 64 + col];
#pragma unroll
                for (int j = 0; j < 4; ++j) {
                    int rl = wave * 32 + m * 16 + lg * 4 + j;
                    float val = fmaxf(acc2[m][n][j] + bb, 0.f);
                    ff1s[rl * 64 + (((col >> 3) ^ (rl & 7)) << 3) + (col & 7)] = f2bf(val);
                }
            }
        }
        // ffn2 partial: h2acc += ff1s @ W2s^T  (K=64)
#pragma unroll
        for (int kk4 = 0; kk4 < 2; ++kk4) {
            int kc = kk4 * 4 + lg;
            short8 a[2], b[8];
#pragma unroll
            for (int m = 0; m < 2; ++m) {
                int r = wave * 32 + m * 16 + lr;
                a[m] = *reinterpret_cast<const short8*>(&ff1s[r * 64 + ((kc ^ (r & 7)) << 3)]);
            }
#pragma unroll
            for (int n = 0; n < 8; ++n) {
                int r = n * 16 + lr;
                b[n] = *reinterpret_cast<const short8*>(&W2s[r * 64 + ((kc ^ (r & 7)) << 3)]);
            }
#pragma unroll
            for (int m = 0; m < 2; ++m)
#pragma unroll
                for (int n = 0; n < 8; ++n)
                    h2acc[m][n] = __builtin_amdgcn_mfma_f32_16x16x32_bf16(a[m], b[n], h2acc[m][n], 0, 0, 0);
        }
    }

    // ---- phase 3: h'' = h2acc + b2 + h' (h32 re-read, L2-hot) ----
#pragma unroll
    for (int m = 0; m < 2; ++m) {
#pragma unroll
        for (int n = 0; n < 8; ++n) {
            int col = n * 16 + lr;
            float bb = b2[col];
#pragma unroll
            for (int j = 0; j < 4; ++j) {
                int row = row0 + wave * 32 + m * 16 + lg * 4 + j;
                if (row < M) {
                    float val = h2acc[m][n][j] + bb + h32[(size_t)row * 128 + col];
                    h32[(size_t)row * 128 + col] = val;
                    hb[(size_t)row * 128 + col] = __float2bfloat16(val);
                }
            }
        }
    }
}

// ------- attention: wave/dst, 8-edge blocked online softmax, fused qkv rows -------
__global__ __launch_bounds__(256) void attn_kernel(const __hip_bfloat16* __restrict__ qkvb,
        const int* __restrict__ off, const int* __restrict__ csr_src,
        __hip_bfloat16* __restrict__ aggb, int n) {
    int wave = threadIdx.x >> 6;
    int lane = threadIdx.x & 63;
    int i = blockIdx.x * 4 + wave;
    if (i >= n) return;
    const unsigned* qv = reinterpret_cast<const unsigned*>(qkvb);
    unsigned ku = qv[(size_t)i * 192 + 64 + lane];
    float kx = __uint_as_float(ku << 16);
    float ky = __uint_as_float(ku & 0xffff0000u);
    int e0 = off[i], e1 = off[i + 1];
    float m = -INFINITY, ssum = 0.f, ax = 0.f, ay = 0.f;
    int e = e0;
    // ---- 8-edge main loop: 16 row loads in flight, one rescale per 8 edges ----
    for (; e + 8 <= e1; e += 8) {
        int s[8];
#pragma unroll
        for (int u = 0; u < 8; ++u) s[u] = csr_src[e + u];
        unsigned q[8], w[8];
#pragma unroll
        for (int u = 0; u < 8; ++u) {
            q[u] = qv[(size_t)s[u] * 192 + lane];
            w[u] = qv[(size_t)s[u] * 192 + 128 + lane];
        }
        float l[8];
#pragma unroll
        for (int u = 0; u < 8; ++u)
            l[u] = __uint_as_float(q[u] << 16) * kx + __uint_as_float(q[u] & 0xffff0000u) * ky;
#pragma unroll
        for (int u = 0; u < 8; ++u) {
            l[u] += __shfl_xor(l[u], 1);
            l[u] += __shfl_xor(l[u], 2);
            l[u] += __shfl_xor(l[u], 4);
            l[u] *= SCALE;
        }
        float mx = fmaxf(fmaxf(fmaxf(l[0], l[1]), fmaxf(l[2], l[3])),
                         fmaxf(fmaxf(l[4], l[5]), fmaxf(l[6], l[7])));
        float mn = fmaxf(m, mx);
        float corr = __expf(m - mn);
        float psum = 0.f, axn = 0.f, ayn = 0.f;
#pragma unroll
        for (int u = 0; u < 8; ++u) {
            float pe = __expf(l[u] - mn);
            psum += pe;
            axn += pe * __uint_as_float(w[u] << 16);
            ayn += pe * __uint_as_float(w[u] & 0xffff0000u);
        }
        ssum = ssum * corr + psum;
        ax = ax * corr + axn;
        ay = ay * corr + ayn;
        m = mn;
    }
    // ---- 4-edge remainder ----
    for (; e + 4 <= e1; e += 4) {
        int s0 = csr_src[e], s1 = csr_src[e + 1], s2 = csr_src[e + 2], s3 = csr_src[e + 3];
        unsigned q0 = qv[(size_t)s0 * 192 + lane];
        unsigned q1 = qv[(size_t)s1 * 192 + lane];
        unsigned q2 = qv[(size_t)s2 * 192 + lane];
        unsigned q3 = qv[(size_t)s3 * 192 + lane];
        unsigned w0 = qv[(size_t)s0 * 192 + 128 + lane];
        unsigned w1 = qv[(size_t)s1 * 192 + 128 + lane];
        unsigned w2 = qv[(size_t)s2 * 192 + 128 + lane];
        unsigned w3 = qv[(size_t)s3 * 192 + 128 + lane];
        float l0 = __uint_as_float(q0 << 16) * kx + __uint_as_float(q0 & 0xffff0000u) * ky;
        float l1 = __uint_as_float(q1 << 16) * kx + __uint_as_float(q1 & 0xffff0000u) * ky;
        float l2 = __uint_as_float(q2 << 16) * kx + __uint_as_float(q2 & 0xffff0000u) * ky;
        float l3 = __uint_as_float(q3 << 16) * kx + __uint_as_float(q3 & 0xffff0000u) * ky;
        l0 += __shfl_xor(l0, 1); l1 += __shfl_xor(l1, 1); l2 += __shfl_xor(l2, 1); l3 += __shfl_xor(l3, 1);
        l0 += __shfl_xor(l0, 2); l1 += __shfl_xor(l1, 2); l2 += __shfl_xor(l2, 2); l3 += __shfl_xor(l3, 2);
        l0 += __shfl_xor(l0, 4); l1 += __shfl_xor(l1, 4); l2 += __shfl_xor(l2, 4); l3 += __shfl_xor(l3, 4);
        l0 *= SCALE; l1 *= SCALE; l2 *= SCALE; l3 *= SCALE;
        float mx = fmaxf(fmaxf(l0, l1), fmaxf(l2, l3));
        float mn = fmaxf(m, mx);
        float corr = __expf(m - mn);
        float p0 = __expf(l0 - mn);
        float p1 = __expf(l1 - mn);
        float p2 = __expf(l2 - mn);
        float p3 = __expf(l3 - mn);
        ssum = ssum * corr + ((p0 + p1) + (p2 + p3));
        ax = ax * corr + p0 * __uint_as_float(w0 << 16) + p1 * __uint_as_float(w1 << 16)
                       + p2 * __uint_as_float(w2 << 16) + p3 * __uint_as_float(w3 << 16);
        ay = ay * corr + p0 * __uint_as_float(w0 & 0xffff0000u) + p1 * __uint_as_float(w1 & 0xffff0000u)
                       + p2 * __uint_as_float(w2 & 0xffff0000u) + p3 * __uint_as_float(w3 & 0xffff0000u);
        m = mn;
    }
    // ---- scalar remainder ----
    for (; e < e1; ++e) {
        int s0 = csr_src[e];
        unsigned q0 = qv[(size_t)s0 * 192 + lane];
        unsigned w0 = qv[(size_t)s0 * 192 + 128 + lane];
        float l0 = __uint_as_float(q0 << 16) * kx + __uint_as_float(q0 & 0xffff0000u) * ky;
        l0 += __shfl_xor(l0, 1); l0 += __shfl_xor(l0, 2); l0 += __shfl_xor(l0, 4);
        l0 *= SCALE;
        float mn = fmaxf(m, l0);
        float corr = __expf(m - mn);
        float pe = __expf(l0 - mn);
        ssum = ssum * corr + pe;
        ax = ax * corr + pe * __uint_as_float(w0 << 16);
        ay = ay * corr + pe * __uint_as_float(w0 & 0xffff0000u);
        m = mn;
    }
    float inv = (ssum > 0.f) ? 1.f / ssum : 0.f;
    __hip_bfloat162 o;
    o.x = __float2bfloat16(ax * inv);
    o.y = __float2bfloat16(ay * inv);
    *reinterpret_cast<__hip_bfloat162*>(aggb + (size_t)i * 128 + lane * 2) = o;
}

// ---------------- pooling (deterministic two-stage, batch sorted) ----------------
__global__ void group_bounds_kernel(const int* __restrict__ batch, int n, int* __restrict__ gstart) {
    int g = threadIdx.x;
    if (g > NG) return;
    int lo = 0, hi = n;
    while (lo < hi) {
        int mid = (lo + hi) >> 1;
        if (batch[mid] < g) lo = mid + 1; else hi = mid;
    }
    gstart[g] = lo;
}

__global__ __launch_bounds__(256) void pool_stage1(const float* __restrict__ h,
        const int* __restrict__ gstart, float* __restrict__ pws) {
    int g = blockIdx.x, sub = blockIdx.y;
    int s = gstart[g], e = gstart[g + 1];
    int c = threadIdx.x & 127;
    int half = threadIdx.x >> 7;
    float acc = 0.f;
    for (int r = s + sub * 2 + half; r < e; r += 16)
        acc += h[(size_t)r * 128 + c];
    __shared__ float tmp[2][128];
    tmp[half][c] = acc;
    __syncthreads();
    if (half == 0)
        pws[((size_t)g * 8 + sub) * 128 + c] = tmp[0][c] + tmp[1][c];
}

__global__ void pool_stage2(const float* __restrict__ pws, const int* __restrict__ gstart,
        float* __restrict__ out) {
    int g = blockIdx.x, c = threadIdx.x;
    float s = 0.f;
#pragma unroll
    for (int i = 0; i < 8; ++i) s += pws[((size_t)g * 8 + i) * 128 + c];
    float cntf = (float)(gstart[g + 1] - gstart[g]);
    out[(size_t)g * 128 + c] = s / fmaxf(cntf, 1.f);
}

extern "C" void kernel_launch(void* const* d_in, const int* in_sizes, int n_in,
                              void* d_out, int out_size, void* d_ws, size_t ws_size,
                              hipStream_t stream) {
    const float* x = (const float*)d_in[0];
    const int* ei = (const int*)d_in[1];
    const int* batch = (const int*)d_in[2];
    const float* W_embed = (const float*)d_in[3];
    const float* Wqk = (const float*)d_in[4];
    const float* Wv = (const float*)d_in[5];
    const float* Wout = (const float*)d_in[6];
    const float* b_out = (const float*)d_in[7];
    const float* W1 = (const float*)d_in[8];
    const float* b1 = (const float*)d_in[9];
    const float* W2 = (const float*)d_in[10];
    const float* b2 = (const float*)d_in[11];

    int Nn = in_sizes[2];
    int E = in_sizes[1] / 2;

    char* p = (char*)d_ws;
    auto alloc = [&](size_t bytes) {
        char* r = p;
        p += (bytes + 255) & ~(size_t)255;
        return r;
    };
    float* h32 = (float*)alloc((size_t)Nn * D * 4);
    __hip_bfloat16* hb = (__hip_bfloat16*)alloc((size_t)Nn * D * 2);
    __hip_bfloat16* aggb = (__hip_bfloat16*)alloc((size_t)Nn * D * 2);
    __hip_bfloat16* qkvb = (__hip_bfloat16*)alloc((size_t)Nn * QKV * 2);
    __hip_bfloat16* xb = (__hip_bfloat16*)alloc((size_t)Nn * D * 2);
    __hip_bfloat16* WembT = (__hip_bfloat16*)alloc((size_t)D * D * 2);
    __hip_bfloat16* WqkvT = (__hip_bfloat16*)alloc((size_t)NL * QKV * D * 2);
    __hip_bfloat16* WoutT = (__hip_bfloat16*)alloc((size_t)NL * D * D * 2);
    __hip_bfloat16* W1T = (__hip_bfloat16*)alloc((size_t)NL * D * DFF * 2);
    __hip_bfloat16* W2T = (__hip_bfloat16*)alloc((size_t)NL * DFF * D * 2);
    int* csr_src = (int*)alloc((size_t)E * 4);
    int* cnt = (int*)alloc((size_t)Nn * 4);
    int* incl = (int*)alloc((size_t)Nn * 4);
    int* off = (int*)alloc(((size_t)Nn + 1) * 4);
    int* cur = (int*)alloc((size_t)Nn * 4);
    int* partials = (int*)alloc(1024 * 4);
    int* gstart = (int*)alloc((NG + 1) * 4);
    float* pws = (float*)alloc((size_t)NG * 8 * 128 * 4);

    const int* e_src = ei;
    const int* e_dst = ei + E;

    // CSR build (by dst)
    hipMemsetAsync(cnt, 0, (size_t)Nn * 4, stream);
    count_kernel<<<(E + 255) / 256, 256, 0, stream>>>(e_dst, cnt, E);
    int nsb = (Nn + 1023) / 1024;
    scan_block_kernel<<<nsb, 1024, 0, stream>>>(cnt, incl, partials, Nn);
    scan_partials_kernel<<<1, 64, 0, stream>>>(partials, nsb);
    finalize_off_kernel<<<(Nn + 255) / 256, 256, 0, stream>>>(cnt, incl, partials, off, cur, Nn, E);
    scatter_kernel<<<(E + 255) / 256, 256, 0, stream>>>(e_src, e_dst, cur, csr_src, E);

    // weight prep
    transpose_cvt_kernel<<<dim3((2 * D * D + 255) / 256, NL), 256, 0, stream>>>(
        Wqk, WqkvT, D, 2 * D, QKV * D);
    transpose_cvt_kernel<<<dim3((D * D + 255) / 256, NL), 256, 0, stream>>>(
        Wv, WqkvT + (size_t)2 * D * D, D, D, QKV * D);
    transpose_cvt_kernel<<<dim3((D * D + 255) / 256, NL), 256, 0, stream>>>(
        Wout, WoutT, D, D, D * D);
    transpose_cvt_kernel<<<dim3((D * DFF + 255) / 256, NL), 256, 0, stream>>>(
        W1, W1T, D, DFF, D * DFF);
    transpose_cvt_kernel<<<dim3((DFF * D + 255) / 256, NL), 256, 0, stream>>>(
        W2, W2T, DFF, D, DFF * D);
    wembT_kernel<<<(128 * 128 + 255) / 256, 256, 0, stream>>>(W_embed, WembT);
    pad_cvt_x_kernel<<<((size_t)Nn * 128 + 255) / 256, 256, 0, stream>>>(x, xb, Nn);

    int gmb = (Nn + 127) / 128;
    // embed via MFMA: h32 + hb = xb @ WembT^T
    gemm_mfma<<<dim3(gmb, D / 64), 256, 0, stream>>>(xb, WembT, h32, hb, Nn, D, D);

    size_t fused_lds = (size_t)(16384 + 16384 + 8192) * sizeof(unsigned short); // 80 KB

    for (int l = 0; l < NL; ++l) {
        gemm_qkv<<<gmb, 256, 0, stream>>>(hb, WqkvT + (size_t)l * QKV * D, qkvb, Nn);
        attn_kernel<<<(Nn + 3) / 4, 256, 0, stream>>>(qkvb, off, csr_src, aggb, Nn);
        fused_out_ffn<<<gmb, 256, fused_lds, stream>>>(
            aggb, WoutT + (size_t)l * D * D, b_out + (size_t)l * D,
            W1T + (size_t)l * D * DFF, b1 + (size_t)l * DFF,
            W2T + (size_t)l * DFF * D, b2 + (size_t)l * D,
            h32, hb, Nn);
    }

    group_bounds_kernel<<<1, 128, 0, stream>>>(batch, Nn, gstart);
    pool_stage1<<<dim3(NG, 8), 256, 0, stream>>>(h32, gstart, pws);
    pool_stage2<<<NG, 128, 0, stream>>>(pws, gstart, (float*)d_out);
}